// Round 1
// baseline (326.090 us; speedup 1.0000x reference)
//
#include <hip/hip_runtime.h>
#include <hip/hip_bf16.h>
#include <cstdint>
#include <cstddef>

typedef __attribute__((ext_vector_type(8))) short bf16x8;
typedef __attribute__((ext_vector_type(4))) float f32x4;

#define LOG2E 1.44269504088896f

__device__ __forceinline__ unsigned short f2bf(float f) {
    unsigned u = __builtin_bit_cast(unsigned, f);
    unsigned r = (u + 0x7FFFu + ((u >> 16) & 1u)) >> 16;
    return (unsigned short)r;
}

// ---------------- f32 -> bf16 convert ----------------
__global__ void cvt_f32_bf16(const float* __restrict__ src, unsigned short* __restrict__ dst, int n) {
    int i = (blockIdx.x * blockDim.x + threadIdx.x) * 4;
    if (i < n) {
        float4 v = *(const float4*)(src + i);
        ushort4 o;
        o.x = f2bf(v.x); o.y = f2bf(v.y); o.z = f2bf(v.z); o.w = f2bf(v.w);
        *(ushort4*)(dst + i) = o;
    }
}

// ---------------- QKV projection GEMM + bias + RoPE ----------------
// C[m,n] = sum_k x[m,k] * W[n,k] + b[n];  M=4096 (b*T+t), N=1024, K=1024
// z=0: Q (rope), z=1: K (rope), z=2: V
__global__ __launch_bounds__(256) void gemm_qkv(
    const unsigned short* __restrict__ xb,
    const unsigned short* __restrict__ wqb,
    const unsigned short* __restrict__ wkb,
    const unsigned short* __restrict__ wvb,
    const float* __restrict__ bq, const float* __restrict__ bk, const float* __restrict__ bv,
    const float* __restrict__ cosT, const float* __restrict__ sinT,
    unsigned short* __restrict__ Qb, unsigned short* __restrict__ Kb, unsigned short* __restrict__ Vb)
{
    const int z = blockIdx.z;
    const unsigned short* wb = (z == 0) ? wqb : ((z == 1) ? wkb : wvb);
    const float* bias = (z == 0) ? bq : ((z == 1) ? bk : bv);
    unsigned short* dst = (z == 0) ? Qb : ((z == 1) ? Kb : Vb);

    __shared__ __align__(16) unsigned short Al[128 * 40];
    __shared__ __align__(16) unsigned short Bl[128 * 40];

    const int tid = threadIdx.x;
    const int lane = tid & 63;
    const int w = tid >> 6;
    const int wr = w >> 1, wc = w & 1;
    const int lr = lane & 15, lg = lane >> 4;
    const int m0 = blockIdx.y * 128;
    const int n0 = blockIdx.x * 128;

    f32x4 acc[4][4] = {};

    for (int k0 = 0; k0 < 1024; k0 += 32) {
        bf16x8 ra[2], rb[2];
#pragma unroll
        for (int p = 0; p < 2; ++p) {
            int u = p * 256 + tid;
            int row = u >> 2, seg = u & 3;
            ra[p] = *(const bf16x8*)(xb + (size_t)(m0 + row) * 1024 + k0 + seg * 8);
            rb[p] = *(const bf16x8*)(wb + (size_t)(n0 + row) * 1024 + k0 + seg * 8);
        }
        __syncthreads();
#pragma unroll
        for (int p = 0; p < 2; ++p) {
            int u = p * 256 + tid;
            int row = u >> 2, seg = u & 3;
            *(bf16x8*)(Al + row * 40 + seg * 8) = ra[p];
            *(bf16x8*)(Bl + row * 40 + seg * 8) = rb[p];
        }
        __syncthreads();
        bf16x8 af[4], bfr[4];
#pragma unroll
        for (int mt = 0; mt < 4; ++mt)
            af[mt] = *(const bf16x8*)(Al + (wr * 64 + mt * 16 + lr) * 40 + lg * 8);
#pragma unroll
        for (int nt = 0; nt < 4; ++nt)
            bfr[nt] = *(const bf16x8*)(Bl + (wc * 64 + nt * 16 + lr) * 40 + lg * 8);
#pragma unroll
        for (int mt = 0; mt < 4; ++mt)
#pragma unroll
            for (int nt = 0; nt < 4; ++nt)
                acc[mt][nt] = __builtin_amdgcn_mfma_f32_16x16x32_bf16(af[mt], bfr[nt], acc[mt][nt], 0, 0, 0);
    }

    const bool dorope = (z < 2);
#pragma unroll
    for (int mt = 0; mt < 4; ++mt) {
#pragma unroll
        for (int nt = 0; nt < 4; ++nt) {
            const int col = n0 + wc * 64 + nt * 16 + lr;
            const float bcol = bias[col];
            const int h = col >> 6, hd = col & 63;
#pragma unroll
            for (int r = 0; r < 4; ++r) {
                const int mrow = m0 + wr * 64 + mt * 16 + lg * 4 + r;
                const int t = mrow & 2047, bb = mrow >> 11;
                float v = acc[mt][nt][r] + bcol;
                float part = __shfl_xor(v, 1);   // partner column (hd^1), same row
                if (dorope) {
                    const int i = hd >> 1;
                    const float c = cosT[t * 32 + i], s = sinT[t * 32 + i];
                    v = (hd & 1) ? (part * s + v * c) : (v * c - part * s);
                }
                dst[((size_t)(bb * 16 + h) * 2048 + t) * 64 + hd] = f2bf(v);
            }
        }
    }
}

// ---------------- Flash attention (causal) ----------------
// Q,K,V: [B*H, T, 64] bf16. Out: attnb [B, T, H*64] bf16.
__global__ __launch_bounds__(256) void attn_fwd(
    const unsigned short* __restrict__ Qb, const unsigned short* __restrict__ Kb,
    const unsigned short* __restrict__ Vb, unsigned short* __restrict__ attnb)
{
    __shared__ __align__(16) unsigned short Kl[2 * 32 * 40]; // [d-half][kv][d32 pad40]
    __shared__ __align__(16) unsigned short Vt[64 * 40];     // [d][kv pad40]
    __shared__ __align__(16) unsigned short Pl[4 * 16 * 40]; // per-wave [q16][kv32 pad40]

    const int tid = threadIdx.x, lane = tid & 63, w = tid >> 6;
    const int lr = lane & 15, lg = lane >> 4;
    const int q0 = blockIdx.x * 64;
    const int bh = blockIdx.y;
    const size_t base = (size_t)bh * 2048 * 64;

    // Q fragments (wave's 16 q-rows), hoisted
    bf16x8 qf[2];
    const int qrow = q0 + w * 16 + lr;
#pragma unroll
    for (int st = 0; st < 2; ++st)
        qf[st] = *(const bf16x8*)(Qb + base + (size_t)qrow * 64 + st * 32 + lg * 8);

    f32x4 o[4] = {};
    float mx[4], sm[4];
#pragma unroll
    for (int r = 0; r < 4; ++r) { mx[r] = -1e30f; sm[r] = 0.f; }

    const int ntile = (q0 >> 5) + 2;
    for (int it = 0; it < ntile; ++it) {
        const int kv0 = it * 32;
        __syncthreads();
        {
            const int kvr = tid >> 3, seg = tid & 7;
            bf16x8 k8 = *(const bf16x8*)(Kb + base + (size_t)(kv0 + kvr) * 64 + seg * 8);
            bf16x8 v8 = *(const bf16x8*)(Vb + base + (size_t)(kv0 + kvr) * 64 + seg * 8);
            const int st = seg >> 2;
            *(bf16x8*)(Kl + st * 1280 + kvr * 40 + (seg & 3) * 8) = k8;
#pragma unroll
            for (int j = 0; j < 8; ++j)
                Vt[(seg * 8 + j) * 40 + kvr] = (unsigned short)v8[j];
        }
        __syncthreads();

        // S = Q K^T (16 q-rows x 32 kv-cols per wave)
        f32x4 s[2] = {};
#pragma unroll
        for (int st = 0; st < 2; ++st)
#pragma unroll
            for (int f = 0; f < 2; ++f) {
                bf16x8 kb = *(const bf16x8*)(Kl + st * 1280 + (f * 16 + lr) * 40 + lg * 8);
                s[f] = __builtin_amdgcn_mfma_f32_16x16x32_bf16(qf[st], kb, s[f], 0, 0, 0);
            }

        // scale + causal mask + row-max (rows live in 16-lane groups)
        float pmax[4];
#pragma unroll
        for (int r = 0; r < 4; ++r) {
            const int row = q0 + w * 16 + lg * 4 + r;
#pragma unroll
            for (int f = 0; f < 2; ++f) {
                const int col = kv0 + f * 16 + lr;
                float sv = s[f][r] * 0.125f;
                s[f][r] = (col <= row) ? sv : -1e30f;
            }
            float v = fmaxf(s[0][r], s[1][r]);
            v = fmaxf(v, __shfl_xor(v, 1, 16));
            v = fmaxf(v, __shfl_xor(v, 2, 16));
            v = fmaxf(v, __shfl_xor(v, 4, 16));
            v = fmaxf(v, __shfl_xor(v, 8, 16));
            pmax[r] = v;
        }

        // online softmax update
#pragma unroll
        for (int r = 0; r < 4; ++r) {
            const float mnew = fmaxf(mx[r], pmax[r]);
            const float alpha = exp2f((mx[r] - mnew) * LOG2E);
            mx[r] = mnew;
            float rs = 0.f;
#pragma unroll
            for (int f = 0; f < 2; ++f) {
                float p = exp2f((s[f][r] - mnew) * LOG2E);
                s[f][r] = p;
                rs += p;
            }
            rs += __shfl_xor(rs, 1, 16);
            rs += __shfl_xor(rs, 2, 16);
            rs += __shfl_xor(rs, 4, 16);
            rs += __shfl_xor(rs, 8, 16);
            sm[r] = sm[r] * alpha + rs;
#pragma unroll
            for (int f = 0; f < 4; ++f)
                o[f][r] *= alpha;
        }

        // P -> bf16 via wave-private LDS, re-fragment as MFMA A operand
#pragma unroll
        for (int r = 0; r < 4; ++r)
#pragma unroll
            for (int f = 0; f < 2; ++f)
                Pl[w * 640 + (lg * 4 + r) * 40 + f * 16 + lr] = f2bf(s[f][r]);
        bf16x8 pa = *(const bf16x8*)(Pl + w * 640 + lr * 40 + lg * 8);
#pragma unroll
        for (int f = 0; f < 4; ++f) {
            bf16x8 vb = *(const bf16x8*)(Vt + (f * 16 + lr) * 40 + lg * 8);
            o[f] = __builtin_amdgcn_mfma_f32_16x16x32_bf16(pa, vb, o[f], 0, 0, 0);
        }
    }

    // normalize + write [B, T, H*64]
    const int b = bh >> 4, h = bh & 15;
#pragma unroll
    for (int r = 0; r < 4; ++r) {
        const float inv = 1.f / sm[r];
        const int trow = q0 + w * 16 + lg * 4 + r;
#pragma unroll
        for (int f = 0; f < 4; ++f)
            attnb[((size_t)(b * 2048 + trow)) * 1024 + h * 64 + f * 16 + lr] = f2bf(o[f][r] * inv);
    }
}

// ---------------- output projection GEMM + bias, f32 out ----------------
__global__ __launch_bounds__(256) void gemm_out(
    const unsigned short* __restrict__ ab,   // [4096][1024] bf16
    const unsigned short* __restrict__ wob,  // [1024][1024] bf16
    const float* __restrict__ bo,
    float* __restrict__ out)
{
    __shared__ __align__(16) unsigned short Al[128 * 40];
    __shared__ __align__(16) unsigned short Bl[128 * 40];

    const int tid = threadIdx.x;
    const int lane = tid & 63;
    const int w = tid >> 6;
    const int wr = w >> 1, wc = w & 1;
    const int lr = lane & 15, lg = lane >> 4;
    const int m0 = blockIdx.y * 128;
    const int n0 = blockIdx.x * 128;

    f32x4 acc[4][4] = {};

    for (int k0 = 0; k0 < 1024; k0 += 32) {
        bf16x8 ra[2], rb[2];
#pragma unroll
        for (int p = 0; p < 2; ++p) {
            int u = p * 256 + tid;
            int row = u >> 2, seg = u & 3;
            ra[p] = *(const bf16x8*)(ab + (size_t)(m0 + row) * 1024 + k0 + seg * 8);
            rb[p] = *(const bf16x8*)(wob + (size_t)(n0 + row) * 1024 + k0 + seg * 8);
        }
        __syncthreads();
#pragma unroll
        for (int p = 0; p < 2; ++p) {
            int u = p * 256 + tid;
            int row = u >> 2, seg = u & 3;
            *(bf16x8*)(Al + row * 40 + seg * 8) = ra[p];
            *(bf16x8*)(Bl + row * 40 + seg * 8) = rb[p];
        }
        __syncthreads();
        bf16x8 af[4], bfr[4];
#pragma unroll
        for (int mt = 0; mt < 4; ++mt)
            af[mt] = *(const bf16x8*)(Al + (wr * 64 + mt * 16 + lr) * 40 + lg * 8);
#pragma unroll
        for (int nt = 0; nt < 4; ++nt)
            bfr[nt] = *(const bf16x8*)(Bl + (wc * 64 + nt * 16 + lr) * 40 + lg * 8);
#pragma unroll
        for (int mt = 0; mt < 4; ++mt)
#pragma unroll
            for (int nt = 0; nt < 4; ++nt)
                acc[mt][nt] = __builtin_amdgcn_mfma_f32_16x16x32_bf16(af[mt], bfr[nt], acc[mt][nt], 0, 0, 0);
    }

#pragma unroll
    for (int mt = 0; mt < 4; ++mt) {
#pragma unroll
        for (int nt = 0; nt < 4; ++nt) {
            const int col = n0 + wc * 64 + nt * 16 + lr;
            const float bcol = bo[col];
#pragma unroll
            for (int r = 0; r < 4; ++r) {
                const int mrow = m0 + wr * 64 + mt * 16 + lg * 4 + r;
                out[(size_t)mrow * 1024 + col] = acc[mt][nt][r] + bcol;
            }
        }
    }
}

extern "C" void kernel_launch(void* const* d_in, const int* in_sizes, int n_in,
                              void* d_out, int out_size, void* d_ws, size_t ws_size,
                              hipStream_t stream) {
    const float* x    = (const float*)d_in[0];
    const float* cosT = (const float*)d_in[1];
    const float* sinT = (const float*)d_in[2];
    const float* Wq   = (const float*)d_in[3];
    const float* bq   = (const float*)d_in[4];
    const float* Wk   = (const float*)d_in[5];
    const float* bk   = (const float*)d_in[6];
    const float* Wv   = (const float*)d_in[7];
    const float* bv   = (const float*)d_in[8];
    const float* Wo   = (const float*)d_in[9];
    const float* bo   = (const float*)d_in[10];
    float* out = (float*)d_out;

    char* ws = (char*)d_ws;
    unsigned short* xb    = (unsigned short*)(ws + 0);          // 8 MB
    unsigned short* wqb   = (unsigned short*)(ws + 8388608);    // 2 MB
    unsigned short* wkb   = (unsigned short*)(ws + 10485760);
    unsigned short* wvb   = (unsigned short*)(ws + 12582912);
    unsigned short* wob   = (unsigned short*)(ws + 14680064);
    unsigned short* Qb    = (unsigned short*)(ws + 16777216);   // 8 MB each
    unsigned short* Kb    = (unsigned short*)(ws + 25165824);
    unsigned short* Vb    = (unsigned short*)(ws + 33554432);
    unsigned short* attnb = (unsigned short*)(ws + 41943040);

    // converts
    cvt_f32_bf16<<<4096, 256, 0, stream>>>(x, xb, 4194304);
    cvt_f32_bf16<<<1024, 256, 0, stream>>>(Wq, wqb, 1048576);
    cvt_f32_bf16<<<1024, 256, 0, stream>>>(Wk, wkb, 1048576);
    cvt_f32_bf16<<<1024, 256, 0, stream>>>(Wv, wvb, 1048576);
    cvt_f32_bf16<<<1024, 256, 0, stream>>>(Wo, wob, 1048576);

    gemm_qkv<<<dim3(8, 32, 3), 256, 0, stream>>>(xb, wqb, wkb, wvb, bq, bk, bv,
                                                 cosT, sinT, Qb, Kb, Vb);
    attn_fwd<<<dim3(32, 32), 256, 0, stream>>>(Qb, Kb, Vb, attnb);
    gemm_out<<<dim3(8, 32, 1), 256, 0, stream>>>(attnb, wob, bo, out);
}

// Round 2
// 191.130 us; speedup vs baseline: 1.7061x; 1.7061x over previous
//
#include <hip/hip_runtime.h>
#include <hip/hip_bf16.h>
#include <cstdint>
#include <cstddef>

typedef __attribute__((ext_vector_type(8))) short bf16x8;
typedef __attribute__((ext_vector_type(4))) float f32x4;

#define SCALE2 0.180336880111112f   // 0.125 * log2(e): softmax done in base-2 domain

__device__ __forceinline__ unsigned short f2bf(float f) {
    unsigned u = __builtin_bit_cast(unsigned, f);
    unsigned r = (u + 0x7FFFu + ((u >> 16) & 1u)) >> 16;
    return (unsigned short)r;
}

__device__ __forceinline__ void gload16(const unsigned short* g, unsigned short* l) {
    __builtin_amdgcn_global_load_lds(
        (const __attribute__((address_space(1))) unsigned int*)(g),
        (__attribute__((address_space(3))) unsigned int*)(l), 16, 0, 0);
}

// ---------------- merged f32 -> bf16 convert (x + 4 weights) ----------------
__global__ void cvt_all(const float* __restrict__ x,
                        const float* __restrict__ wq, const float* __restrict__ wk,
                        const float* __restrict__ wv, const float* __restrict__ wo,
                        unsigned short* __restrict__ xb,
                        unsigned short* __restrict__ wqb, unsigned short* __restrict__ wkb,
                        unsigned short* __restrict__ wvb, unsigned short* __restrict__ wob)
{
    const int y = blockIdx.y;
    const float* src; unsigned short* dst; int n;
    switch (y) {
        case 0: src = x;  dst = xb;  n = 4194304; break;
        case 1: src = wq; dst = wqb; n = 1048576; break;
        case 2: src = wk; dst = wkb; n = 1048576; break;
        case 3: src = wv; dst = wvb; n = 1048576; break;
        default: src = wo; dst = wob; n = 1048576; break;
    }
    const int i = (blockIdx.x * 256 + threadIdx.x) * 4;
    if (i < n) {
        float4 v = *(const float4*)(src + i);
        ushort4 o;
        o.x = f2bf(v.x); o.y = f2bf(v.y); o.z = f2bf(v.z); o.w = f2bf(v.w);
        *(ushort4*)(dst + i) = o;
    }
}

// ---------------- QKV projection GEMM + bias + RoPE (m97-style staging) ----------------
__global__ __launch_bounds__(256) void gemm_qkv(
    const unsigned short* __restrict__ xb,
    const unsigned short* __restrict__ wqb,
    const unsigned short* __restrict__ wkb,
    const unsigned short* __restrict__ wvb,
    const float* __restrict__ bq, const float* __restrict__ bk, const float* __restrict__ bv,
    const float* __restrict__ cosT, const float* __restrict__ sinT,
    unsigned short* __restrict__ Qb, unsigned short* __restrict__ Kb, unsigned short* __restrict__ Vb)
{
    const int z = blockIdx.z;
    const unsigned short* wb = (z == 0) ? wqb : ((z == 1) ? wkb : wvb);
    const float* bias = (z == 0) ? bq : ((z == 1) ? bk : bv);
    unsigned short* dst = (z == 0) ? Qb : ((z == 1) ? Kb : Vb);

    __shared__ __align__(16) unsigned short Al[128 * 32];
    __shared__ __align__(16) unsigned short Bl[128 * 32];

    const int tid = threadIdx.x;
    const int lane = tid & 63;
    const int w = tid >> 6;
    const int wr = w >> 1, wc = w & 1;
    const int lr = lane & 15, lg = lane >> 4;
    const int m0 = blockIdx.y * 128;
    const int n0 = blockIdx.x * 128;
    const int srow = tid >> 2, sseg = tid & 3;
    const int wbase = tid & 192;   // w*64

    f32x4 acc[4][4] = {};

    for (int k0 = 0; k0 < 1024; k0 += 32) {
        __syncthreads();
#pragma unroll
        for (int p = 0; p < 2; ++p) {
            const int row = srow + p * 64;
            gload16(xb + (size_t)(m0 + row) * 1024 + k0 + sseg * 8, Al + (p * 256 + wbase) * 8);
            gload16(wb + (size_t)(n0 + row) * 1024 + k0 + sseg * 8, Bl + (p * 256 + wbase) * 8);
        }
        __syncthreads();
        bf16x8 af[4], bfr[4];
#pragma unroll
        for (int mt = 0; mt < 4; ++mt)
            af[mt] = *(const bf16x8*)(Al + (wr * 64 + mt * 16 + lr) * 32 + lg * 8);
#pragma unroll
        for (int nt = 0; nt < 4; ++nt)
            bfr[nt] = *(const bf16x8*)(Bl + (wc * 64 + nt * 16 + lr) * 32 + lg * 8);
#pragma unroll
        for (int mt = 0; mt < 4; ++mt)
#pragma unroll
            for (int nt = 0; nt < 4; ++nt)
                acc[mt][nt] = __builtin_amdgcn_mfma_f32_16x16x32_bf16(af[mt], bfr[nt], acc[mt][nt], 0, 0, 0);
    }

    const bool dorope = (z < 2);
#pragma unroll
    for (int mt = 0; mt < 4; ++mt) {
#pragma unroll
        for (int nt = 0; nt < 4; ++nt) {
            const int col = n0 + wc * 64 + nt * 16 + lr;
            const float bcol = bias[col];
            const int h = col >> 6, hd = col & 63;
#pragma unroll
            for (int r = 0; r < 4; ++r) {
                const int mrow = m0 + wr * 64 + mt * 16 + lg * 4 + r;
                const int t = mrow & 2047, bb = mrow >> 11;
                float v = acc[mt][nt][r] + bcol;
                float part = __shfl_xor(v, 1);   // partner column (hd^1), same row
                if (dorope) {
                    const int i = hd >> 1;
                    const float c = cosT[t * 32 + i], s = sinT[t * 32 + i];
                    v = (hd & 1) ? (part * s + v * c) : (v * c - part * s);
                }
                dst[((size_t)(bb * 16 + h) * 2048 + t) * 64 + hd] = f2bf(v);
            }
        }
    }
}

// ---------------- V transpose: [bh][2048][64] -> [bh][64][2048] ----------------
__global__ __launch_bounds__(256) void transpose_v(const unsigned short* __restrict__ Vb,
                                                   unsigned short* __restrict__ Vtg)
{
    __shared__ __align__(16) unsigned short tl[64 * 72];
    const int tid = threadIdx.x;
    const int bh = blockIdx.y, t0 = blockIdx.x * 64;
    const size_t base = (size_t)bh * 131072;
#pragma unroll
    for (int p = 0; p < 2; ++p) {
        const int u = p * 256 + tid;
        const int row = u >> 3, seg = u & 7;
        *(bf16x8*)(tl + row * 72 + seg * 8) =
            *(const bf16x8*)(Vb + base + (size_t)(t0 + row) * 64 + seg * 8);
    }
    __syncthreads();
#pragma unroll
    for (int p = 0; p < 2; ++p) {
        const int u = p * 256 + tid;
        const int d = u >> 3, seg = u & 7;
        bf16x8 vv;
#pragma unroll
        for (int j = 0; j < 8; ++j)
            vv[j] = (short)tl[(seg * 8 + j) * 72 + d];
        *(bf16x8*)(Vtg + base + (size_t)d * 2048 + t0 + seg * 8) = vv;
    }
}

// ---------------- Flash attention (causal), KVBLK=64, 32 q-rows/wave ----------------
__global__ __launch_bounds__(256) void attn_fwd(
    const unsigned short* __restrict__ Qb, const unsigned short* __restrict__ Kb,
    const unsigned short* __restrict__ Vtg, unsigned short* __restrict__ attnb)
{
    __shared__ __align__(16) unsigned short Kl[64 * 72];   // [kv][d] pitch 72
    __shared__ __align__(16) unsigned short Vl[64 * 72];   // [d][kv] pitch 72
    __shared__ __align__(16) unsigned short Pl[8 * 16 * 72]; // per (wave,qt): [q16][kv64] pitch 72

    const int tid = threadIdx.x, lane = tid & 63, w = tid >> 6;
    const int lr = lane & 15, lg = lane >> 4;
    const int bh = blockIdx.x;
    const int q0 = (15 - (int)blockIdx.y) * 128;   // heavy blocks dispatched first
    const size_t base = (size_t)bh * 131072;
    const int srow = tid >> 3, sseg = tid & 7;

    bf16x8 qf[2][2];
#pragma unroll
    for (int qt = 0; qt < 2; ++qt)
#pragma unroll
        for (int st = 0; st < 2; ++st)
            qf[qt][st] = *(const bf16x8*)(Qb + base + (size_t)(q0 + w * 32 + qt * 16 + lr) * 64 + st * 32 + lg * 8);

    f32x4 o[2][4] = {};
    float mx[2][4], sm[2][4];
#pragma unroll
    for (int qt = 0; qt < 2; ++qt)
#pragma unroll
        for (int r = 0; r < 4; ++r) { mx[qt][r] = -1e30f; sm[qt][r] = 0.f; }

    const int ntile = (q0 >> 6) + 2;

    // prefetch tile 0 into regs
    bf16x8 kst[2], vst[2];
#pragma unroll
    for (int p = 0; p < 2; ++p) {
        const int row = srow + p * 32;
        kst[p] = *(const bf16x8*)(Kb + base + (size_t)row * 64 + sseg * 8);
        vst[p] = *(const bf16x8*)(Vtg + base + (size_t)row * 2048 + sseg * 8);
    }

    for (int it = 0; it < ntile; ++it) {
        const int kv0 = it << 6;
        __syncthreads();   // prev-iter LDS reads complete
#pragma unroll
        for (int p = 0; p < 2; ++p) {
            const int row = srow + p * 32;
            *(bf16x8*)(Kl + row * 72 + sseg * 8) = kst[p];
            *(bf16x8*)(Vl + row * 72 + sseg * 8) = vst[p];
        }
        if (it + 1 < ntile) {   // software-pipeline next tile's loads over this tile's compute
            const int nkv = kv0 + 64;
#pragma unroll
            for (int p = 0; p < 2; ++p) {
                const int row = srow + p * 32;
                kst[p] = *(const bf16x8*)(Kb + base + (size_t)(nkv + row) * 64 + sseg * 8);
                vst[p] = *(const bf16x8*)(Vtg + base + (size_t)row * 2048 + nkv + sseg * 8);
            }
        }
        __syncthreads();   // tile ready

        // ---- phase A: QK^T + online softmax + P->LDS ----
        bf16x8 kf[4][2];
#pragma unroll
        for (int f = 0; f < 4; ++f)
#pragma unroll
            for (int st = 0; st < 2; ++st)
                kf[f][st] = *(const bf16x8*)(Kl + (f * 16 + lr) * 72 + st * 32 + lg * 8);

#pragma unroll
        for (int qt = 0; qt < 2; ++qt) {
            const int wq = q0 + w * 32 + qt * 16;
            if (kv0 > wq + 15) continue;   // fully masked for this wave's qt rows
            f32x4 s[4] = {};
#pragma unroll
            for (int st = 0; st < 2; ++st)
#pragma unroll
                for (int f = 0; f < 4; ++f)
                    s[f] = __builtin_amdgcn_mfma_f32_16x16x32_bf16(qf[qt][st], kf[f][st], s[f], 0, 0, 0);
            const bool diag = (kv0 + 63 > wq);
            float pmax[4];
#pragma unroll
            for (int r = 0; r < 4; ++r) {
                const int row = wq + lg * 4 + r;
#pragma unroll
                for (int f = 0; f < 4; ++f) {
                    float sv = s[f][r] * SCALE2;
                    if (diag) { const int col = kv0 + f * 16 + lr; sv = (col <= row) ? sv : -1e30f; }
                    s[f][r] = sv;
                }
                float v = fmaxf(fmaxf(s[0][r], s[1][r]), fmaxf(s[2][r], s[3][r]));
                v = fmaxf(v, __shfl_xor(v, 1, 16));
                v = fmaxf(v, __shfl_xor(v, 2, 16));
                v = fmaxf(v, __shfl_xor(v, 4, 16));
                v = fmaxf(v, __shfl_xor(v, 8, 16));
                pmax[r] = v;
            }
            const int po = (w * 2 + qt) * (16 * 72);
#pragma unroll
            for (int r = 0; r < 4; ++r) {
                const float mnew = fmaxf(mx[qt][r], pmax[r]);
                const float alpha = exp2f(mx[qt][r] - mnew);
                mx[qt][r] = mnew;
                float rs = 0.f;
#pragma unroll
                for (int f = 0; f < 4; ++f) {
                    const float p = exp2f(s[f][r] - mnew);
                    s[f][r] = p;
                    rs += p;
                }
                rs += __shfl_xor(rs, 1, 16);
                rs += __shfl_xor(rs, 2, 16);
                rs += __shfl_xor(rs, 4, 16);
                rs += __shfl_xor(rs, 8, 16);
                sm[qt][r] = sm[qt][r] * alpha + rs;
#pragma unroll
                for (int f = 0; f < 4; ++f) o[qt][f][r] *= alpha;
#pragma unroll
                for (int f = 0; f < 4; ++f)
                    Pl[po + (lg * 4 + r) * 72 + f * 16 + lr] = f2bf(s[f][r]);
            }
        }

        // ---- phase B: PV ----
        bf16x8 vf[4][2];
#pragma unroll
        for (int f = 0; f < 4; ++f)
#pragma unroll
            for (int st = 0; st < 2; ++st)
                vf[f][st] = *(const bf16x8*)(Vl + (f * 16 + lr) * 72 + st * 32 + lg * 8);
#pragma unroll
        for (int qt = 0; qt < 2; ++qt) {
            const int wq = q0 + w * 32 + qt * 16;
            if (kv0 > wq + 15) continue;
            const int po = (w * 2 + qt) * (16 * 72);
            bf16x8 pa[2];
#pragma unroll
            for (int st = 0; st < 2; ++st)
                pa[st] = *(const bf16x8*)(Pl + po + lr * 72 + st * 32 + lg * 8);
#pragma unroll
            for (int f = 0; f < 4; ++f)
#pragma unroll
                for (int st = 0; st < 2; ++st)
                    o[qt][f] = __builtin_amdgcn_mfma_f32_16x16x32_bf16(pa[st], vf[f][st], o[qt][f], 0, 0, 0);
        }
    }

    const int b = bh >> 4, h = bh & 15;
#pragma unroll
    for (int qt = 0; qt < 2; ++qt)
#pragma unroll
        for (int r = 0; r < 4; ++r) {
            const float inv = 1.f / sm[qt][r];
            const int trow = q0 + w * 32 + qt * 16 + lg * 4 + r;
#pragma unroll
            for (int f = 0; f < 4; ++f)
                attnb[((size_t)(b * 2048 + trow)) * 1024 + h * 64 + f * 16 + lr] = f2bf(o[qt][f][r] * inv);
        }
}

// ---------------- output projection GEMM + bias, f32 out ----------------
__global__ __launch_bounds__(256) void gemm_out(
    const unsigned short* __restrict__ ab,
    const unsigned short* __restrict__ wob,
    const float* __restrict__ bo,
    float* __restrict__ out)
{
    __shared__ __align__(16) unsigned short Al[128 * 32];
    __shared__ __align__(16) unsigned short Bl[128 * 32];

    const int tid = threadIdx.x;
    const int lane = tid & 63;
    const int w = tid >> 6;
    const int wr = w >> 1, wc = w & 1;
    const int lr = lane & 15, lg = lane >> 4;
    const int m0 = blockIdx.y * 128;
    const int n0 = blockIdx.x * 128;
    const int srow = tid >> 2, sseg = tid & 3;
    const int wbase = tid & 192;

    f32x4 acc[4][4] = {};

    for (int k0 = 0; k0 < 1024; k0 += 32) {
        __syncthreads();
#pragma unroll
        for (int p = 0; p < 2; ++p) {
            const int row = srow + p * 64;
            gload16(ab + (size_t)(m0 + row) * 1024 + k0 + sseg * 8, Al + (p * 256 + wbase) * 8);
            gload16(wob + (size_t)(n0 + row) * 1024 + k0 + sseg * 8, Bl + (p * 256 + wbase) * 8);
        }
        __syncthreads();
        bf16x8 af[4], bfr[4];
#pragma unroll
        for (int mt = 0; mt < 4; ++mt)
            af[mt] = *(const bf16x8*)(Al + (wr * 64 + mt * 16 + lr) * 32 + lg * 8);
#pragma unroll
        for (int nt = 0; nt < 4; ++nt)
            bfr[nt] = *(const bf16x8*)(Bl + (wc * 64 + nt * 16 + lr) * 32 + lg * 8);
#pragma unroll
        for (int mt = 0; mt < 4; ++mt)
#pragma unroll
            for (int nt = 0; nt < 4; ++nt)
                acc[mt][nt] = __builtin_amdgcn_mfma_f32_16x16x32_bf16(af[mt], bfr[nt], acc[mt][nt], 0, 0, 0);
    }

#pragma unroll
    for (int mt = 0; mt < 4; ++mt) {
#pragma unroll
        for (int nt = 0; nt < 4; ++nt) {
            const int col = n0 + wc * 64 + nt * 16 + lr;
            const float bcol = bo[col];
#pragma unroll
            for (int r = 0; r < 4; ++r) {
                const int mrow = m0 + wr * 64 + mt * 16 + lg * 4 + r;
                out[(size_t)mrow * 1024 + col] = acc[mt][nt][r] + bcol;
            }
        }
    }
}

extern "C" void kernel_launch(void* const* d_in, const int* in_sizes, int n_in,
                              void* d_out, int out_size, void* d_ws, size_t ws_size,
                              hipStream_t stream) {
    const float* x    = (const float*)d_in[0];
    const float* cosT = (const float*)d_in[1];
    const float* sinT = (const float*)d_in[2];
    const float* Wq   = (const float*)d_in[3];
    const float* bq   = (const float*)d_in[4];
    const float* Wk   = (const float*)d_in[5];
    const float* bk   = (const float*)d_in[6];
    const float* Wv   = (const float*)d_in[7];
    const float* bv   = (const float*)d_in[8];
    const float* Wo   = (const float*)d_in[9];
    const float* bo   = (const float*)d_in[10];
    float* out = (float*)d_out;

    char* ws = (char*)d_ws;
    // layout (48 MB total, with overlays):
    unsigned short* xb    = (unsigned short*)(ws + 0);           // 8 MB, dead after gemm_qkv
    unsigned short* attnb = (unsigned short*)(ws + 0);           // overlays xb
    unsigned short* wob   = (unsigned short*)(ws + 8388608);     // 2 MB, persistent
    unsigned short* wqb   = (unsigned short*)(ws + 10485760);    // 2 MB
    unsigned short* wkb   = (unsigned short*)(ws + 12582912);
    unsigned short* wvb   = (unsigned short*)(ws + 14680064);
    unsigned short* Qb    = (unsigned short*)(ws + 16777216);    // 8 MB
    unsigned short* Kb    = (unsigned short*)(ws + 25165824);    // 8 MB
    unsigned short* Vb    = (unsigned short*)(ws + 33554432);    // 8 MB, dead after transpose
    unsigned short* Vtg   = (unsigned short*)(ws + 41943040);    // 8 MB

    cvt_all<<<dim3(4096, 5), 256, 0, stream>>>(x, Wq, Wk, Wv, Wo, xb, wqb, wkb, wvb, wob);
    gemm_qkv<<<dim3(8, 32, 3), 256, 0, stream>>>(xb, wqb, wkb, wvb, bq, bk, bv,
                                                 cosT, sinT, Qb, Kb, Vb);
    transpose_v<<<dim3(32, 32), 256, 0, stream>>>(Vb, Vtg);
    attn_fwd<<<dim3(32, 16), 256, 0, stream>>>(Qb, Kb, Vtg, attnb);
    gemm_out<<<dim3(8, 32, 1), 256, 0, stream>>>(attnb, wob, bo, out);
}

// Round 3
// 149.153 us; speedup vs baseline: 2.1863x; 1.2814x over previous
//
#include <hip/hip_runtime.h>
#include <hip/hip_bf16.h>
#include <cstdint>
#include <cstddef>

typedef __attribute__((ext_vector_type(8))) short bf16x8;
typedef __attribute__((ext_vector_type(4))) float f32x4;
typedef __attribute__((ext_vector_type(16))) float f32x16;

#define SCALE2 0.180336880111112f   // 0.125 * log2(e): softmax in base-2 domain

__device__ __forceinline__ unsigned short f2bf(float f) {
    unsigned u = __builtin_bit_cast(unsigned, f);
    unsigned r = (u + 0x7FFFu + ((u >> 16) & 1u)) >> 16;
    return (unsigned short)r;
}

__device__ __forceinline__ void gload16(const unsigned short* g, unsigned short* l) {
    __builtin_amdgcn_global_load_lds(
        (const __attribute__((address_space(1))) unsigned int*)(g),
        (__attribute__((address_space(3))) unsigned int*)(l), 16, 0, 0);
}

// ---------------- merged f32 -> bf16 convert (x + 4 weights) ----------------
__global__ void cvt_all(const float* __restrict__ x,
                        const float* __restrict__ wq, const float* __restrict__ wk,
                        const float* __restrict__ wv, const float* __restrict__ wo,
                        unsigned short* __restrict__ xb,
                        unsigned short* __restrict__ wqb, unsigned short* __restrict__ wkb,
                        unsigned short* __restrict__ wvb, unsigned short* __restrict__ wob)
{
    const int y = blockIdx.y;
    const float* src; unsigned short* dst; int n;
    switch (y) {
        case 0: src = x;  dst = xb;  n = 4194304; break;
        case 1: src = wq; dst = wqb; n = 1048576; break;
        case 2: src = wk; dst = wkb; n = 1048576; break;
        case 3: src = wv; dst = wvb; n = 1048576; break;
        default: src = wo; dst = wob; n = 1048576; break;
    }
    const int i = (blockIdx.x * 256 + threadIdx.x) * 4;
    if (i < n) {
        float4 v = *(const float4*)(src + i);
        ushort4 o;
        o.x = f2bf(v.x); o.y = f2bf(v.y); o.z = f2bf(v.z); o.w = f2bf(v.w);
        *(ushort4*)(dst + i) = o;
    }
}

// ---------------- QKV projection GEMM + bias + RoPE ----------------
// z=0: Q (rope, pre-scaled by SCALE2) -> Qb [bh][t][64]
// z=1: K (rope)                       -> Kb [bh][t][64]
// z=2: V                              -> Vtg [bh][64][t]   (transposed!)
__global__ __launch_bounds__(256) void gemm_qkv(
    const unsigned short* __restrict__ xb,
    const unsigned short* __restrict__ wqb,
    const unsigned short* __restrict__ wkb,
    const unsigned short* __restrict__ wvb,
    const float* __restrict__ bq, const float* __restrict__ bk, const float* __restrict__ bv,
    const float* __restrict__ cosT, const float* __restrict__ sinT,
    unsigned short* __restrict__ Qb, unsigned short* __restrict__ Kb, unsigned short* __restrict__ Vtg)
{
    const int z = blockIdx.z;
    const unsigned short* wb = (z == 0) ? wqb : ((z == 1) ? wkb : wvb);
    const float* bias = (z == 0) ? bq : ((z == 1) ? bk : bv);
    unsigned short* dst = (z == 0) ? Qb : Kb;

    __shared__ __align__(16) unsigned short Al[128 * 32];
    __shared__ __align__(16) unsigned short Bl[128 * 32];

    const int tid = threadIdx.x;
    const int lane = tid & 63;
    const int w = tid >> 6;
    const int wr = w >> 1, wc = w & 1;
    const int lr = lane & 15, lg = lane >> 4;
    const int m0 = blockIdx.y * 128;
    const int n0 = blockIdx.x * 128;
    const int srow = tid >> 2, sseg = tid & 3;
    const int wbase = tid & 192;   // w*64

    f32x4 acc[4][4] = {};

    for (int k0 = 0; k0 < 1024; k0 += 32) {
        __syncthreads();
#pragma unroll
        for (int p = 0; p < 2; ++p) {
            const int row = srow + p * 64;
            gload16(xb + (size_t)(m0 + row) * 1024 + k0 + sseg * 8, Al + (p * 256 + wbase) * 8);
            gload16(wb + (size_t)(n0 + row) * 1024 + k0 + sseg * 8, Bl + (p * 256 + wbase) * 8);
        }
        __syncthreads();
        bf16x8 af[4], bfr[4];
#pragma unroll
        for (int mt = 0; mt < 4; ++mt)
            af[mt] = *(const bf16x8*)(Al + (wr * 64 + mt * 16 + lr) * 32 + lg * 8);
#pragma unroll
        for (int nt = 0; nt < 4; ++nt)
            bfr[nt] = *(const bf16x8*)(Bl + (wc * 64 + nt * 16 + lr) * 32 + lg * 8);
#pragma unroll
        for (int mt = 0; mt < 4; ++mt)
#pragma unroll
            for (int nt = 0; nt < 4; ++nt)
                acc[mt][nt] = __builtin_amdgcn_mfma_f32_16x16x32_bf16(af[mt], bfr[nt], acc[mt][nt], 0, 0, 0);
    }

#pragma unroll
    for (int mt = 0; mt < 4; ++mt) {
#pragma unroll
        for (int nt = 0; nt < 4; ++nt) {
            const int col = n0 + wc * 64 + nt * 16 + lr;
            const float bcol = bias[col];
            const int h = col >> 6, hd = col & 63;
            if (z == 2) {
                const int t0i = m0 + wr * 64 + mt * 16 + lg * 4;
                const int t0 = t0i & 2047, bb = t0i >> 11;
                ushort4 o4;
                o4.x = f2bf(acc[mt][nt][0] + bcol);
                o4.y = f2bf(acc[mt][nt][1] + bcol);
                o4.z = f2bf(acc[mt][nt][2] + bcol);
                o4.w = f2bf(acc[mt][nt][3] + bcol);
                *(ushort4*)(Vtg + ((size_t)(bb * 16 + h) * 64 + hd) * 2048 + t0) = o4;
            } else {
#pragma unroll
                for (int r = 0; r < 4; ++r) {
                    const int mrow = m0 + wr * 64 + mt * 16 + lg * 4 + r;
                    const int t = mrow & 2047, bb = mrow >> 11;
                    float v = acc[mt][nt][r] + bcol;
                    float part = __shfl_xor(v, 1);   // partner column (hd^1), same row
                    const int i = hd >> 1;
                    const float c = cosT[t * 32 + i], s = sinT[t * 32 + i];
                    v = (hd & 1) ? (part * s + v * c) : (v * c - part * s);
                    if (z == 0) v *= SCALE2;
                    dst[((size_t)(bb * 16 + h) * 2048 + t) * 64 + hd] = f2bf(v);
                }
            }
        }
    }
}

// ---------------- Flash attention (causal), swapped-QK^T 32x32 structure ----------------
// Per wave: 32 q-rows. S^T = mfma(K, Q) -> q lane-local; softmax in-register;
// P -> bf16 B-frags via cvt_pk + permlane32_swap; O^T = mfma(V^T, P^T).
__global__ __launch_bounds__(256) void attn_fwd(
    const unsigned short* __restrict__ Qb, const unsigned short* __restrict__ Kb,
    const unsigned short* __restrict__ Vtg, unsigned short* __restrict__ attnb)
{
    __shared__ __align__(16) unsigned short Kl[64 * 64];  // [kv][d], XOR-swizzled
    __shared__ __align__(16) unsigned short Vl[64 * 64];  // [d][kv], XOR-swizzled

    const int tid = threadIdx.x, lane = tid & 63, w = tid >> 6;
    const int l31 = lane & 31, lh = lane >> 5;
    const int bh = blockIdx.x;
    const int q0 = (15 - (int)blockIdx.y) * 128;   // heavy blocks dispatched first
    const size_t base = (size_t)bh * 131072;
    const int wq = q0 + w * 32;
    const int myq = wq + l31;

    // Q as MFMA B-operand frags: lane holds col q=myq, k rows d = s*16 + lh*8 + j
    bf16x8 qf[4];
#pragma unroll
    for (int s = 0; s < 4; ++s)
        qf[s] = *(const bf16x8*)(Qb + base + (size_t)myq * 64 + s * 16 + lh * 8);

    f32x16 ot0 = {}, ot1 = {};   // O^T acc, d-blocks 0/1 (static names: rule #20)
    float mx = -1e30f, sm = 0.f;

    const int ntile = (q0 >> 6) + 2;
    const int srow = tid >> 3, sseg = tid & 7;

    bf16x8 kst[2], vst[2];
#pragma unroll
    for (int p = 0; p < 2; ++p) {
        const int row = srow + p * 32;
        kst[p] = *(const bf16x8*)(Kb + base + (size_t)row * 64 + sseg * 8);
        vst[p] = *(const bf16x8*)(Vtg + base + (size_t)row * 2048 + sseg * 8);
    }

    for (int it = 0; it < ntile; ++it) {
        const int kv0 = it << 6;
        __syncthreads();
#pragma unroll
        for (int p = 0; p < 2; ++p) {
            const int row = srow + p * 32;
            const int slot = sseg ^ (row & 7);
            *(bf16x8*)(Kl + row * 64 + slot * 8) = kst[p];
            *(bf16x8*)(Vl + row * 64 + slot * 8) = vst[p];
        }
        if (it + 1 < ntile) {
            const int nkv = kv0 + 64;
#pragma unroll
            for (int p = 0; p < 2; ++p) {
                const int row = srow + p * 32;
                kst[p] = *(const bf16x8*)(Kb + base + (size_t)(nkv + row) * 64 + sseg * 8);
                vst[p] = *(const bf16x8*)(Vtg + base + (size_t)row * 2048 + nkv + sseg * 8);
            }
        }
        __syncthreads();

#pragma unroll
        for (int kb = 0; kb < 2; ++kb) {
            const int kvb = kv0 + kb * 32;
            if (kvb > wq + 31) continue;   // fully masked for this wave

            // S^T[kv][q] = K x Q
            f32x16 st = {};
#pragma unroll
            for (int s = 0; s < 4; ++s) {
                const int row = kb * 32 + l31;
                const int slot = (s * 2 + lh) ^ (row & 7);
                bf16x8 kf = *(const bf16x8*)(Kl + row * 64 + slot * 8);
                st = __builtin_amdgcn_mfma_f32_32x32x16_bf16(kf, qf[s], st, 0, 0, 0);
            }

            // causal mask (diag tiles only); Q pre-scaled, so st already in base-2 domain
            if (kvb + 31 > wq) {
#pragma unroll
                for (int r = 0; r < 16; ++r) {
                    const int kv = kvb + (r & 3) + 8 * (r >> 2) + 4 * lh;
                    st[r] = (kv <= myq) ? st[r] : -1e30f;
                }
            }

            // row max: in-register + one cross-half exchange
            float pmax = st[0];
#pragma unroll
            for (int r = 1; r < 16; ++r) pmax = fmaxf(pmax, st[r]);
            pmax = fmaxf(pmax, __shfl_xor(pmax, 32));

            // online update with defer-max (T13, THR=8 in base-2)
            if (__ballot(pmax > mx + 8.f)) {
                const float mnew = fmaxf(mx, pmax);
                const float alpha = exp2f(mx - mnew);
                mx = mnew;
                sm *= alpha;
#pragma unroll
                for (int r = 0; r < 16; ++r) { ot0[r] *= alpha; ot1[r] *= alpha; }
            }

            float rs = 0.f;
#pragma unroll
            for (int r = 0; r < 16; ++r) {
                st[r] = exp2f(st[r] - mx);
                rs += st[r];
            }
            sm += rs + __shfl_xor(rs, 32);

            // P -> bf16 B-frags (T12): per 16-kv slice, 4 cvt_pk + 2 permlane32_swap
            unsigned pw[2][4];
#pragma unroll
            for (int s2 = 0; s2 < 2; ++s2) {
                const int o = s2 * 8;
                unsigned a0, a1, b0, b1;
                asm("v_cvt_pk_bf16_f32 %0, %1, %2" : "=v"(a0) : "v"(st[o + 0]), "v"(st[o + 1]));
                asm("v_cvt_pk_bf16_f32 %0, %1, %2" : "=v"(a1) : "v"(st[o + 2]), "v"(st[o + 3]));
                asm("v_cvt_pk_bf16_f32 %0, %1, %2" : "=v"(b0) : "v"(st[o + 4]), "v"(st[o + 5]));
                asm("v_cvt_pk_bf16_f32 %0, %1, %2" : "=v"(b1) : "v"(st[o + 6]), "v"(st[o + 7]));
                asm("v_permlane32_swap_b32 %0, %1" : "+v"(a0), "+v"(b0));
                asm("v_permlane32_swap_b32 %0, %1" : "+v"(a1), "+v"(b1));
                pw[s2][0] = a0; pw[s2][1] = a1; pw[s2][2] = b0; pw[s2][3] = b1;
            }

            // O^T += V^T x P^T
#pragma unroll
            for (int s2 = 0; s2 < 2; ++s2) {
                const int ks = kb * 2 + s2;
                uint4 pk4 = make_uint4(pw[s2][0], pw[s2][1], pw[s2][2], pw[s2][3]);
                bf16x8 pf = __builtin_bit_cast(bf16x8, pk4);
                {
                    const int row = l31;
                    const int slot = (ks * 2 + lh) ^ (row & 7);
                    bf16x8 vf = *(const bf16x8*)(Vl + row * 64 + slot * 8);
                    ot0 = __builtin_amdgcn_mfma_f32_32x32x16_bf16(vf, pf, ot0, 0, 0, 0);
                }
                {
                    const int row = 32 + l31;
                    const int slot = (ks * 2 + lh) ^ (row & 7);
                    bf16x8 vf = *(const bf16x8*)(Vl + row * 64 + slot * 8);
                    ot1 = __builtin_amdgcn_mfma_f32_32x32x16_bf16(vf, pf, ot1, 0, 0, 0);
                }
            }
        }
    }

    // normalize + write [B, T, H*64]; O^T reg r -> d = db*32 + (r&3) + 8*(r>>2) + 4*lh
    const int b = bh >> 4, h = bh & 15;
    const float inv = 1.f / sm;
    unsigned short* obase = attnb + ((size_t)(b * 2048 + myq)) * 1024 + h * 64;
#pragma unroll
    for (int g = 0; g < 4; ++g) {
        ushort4 o4;
        o4.x = f2bf(ot0[g * 4 + 0] * inv);
        o4.y = f2bf(ot0[g * 4 + 1] * inv);
        o4.z = f2bf(ot0[g * 4 + 2] * inv);
        o4.w = f2bf(ot0[g * 4 + 3] * inv);
        *(ushort4*)(obase + g * 8 + lh * 4) = o4;
    }
#pragma unroll
    for (int g = 0; g < 4; ++g) {
        ushort4 o4;
        o4.x = f2bf(ot1[g * 4 + 0] * inv);
        o4.y = f2bf(ot1[g * 4 + 1] * inv);
        o4.z = f2bf(ot1[g * 4 + 2] * inv);
        o4.w = f2bf(ot1[g * 4 + 3] * inv);
        *(ushort4*)(obase + 32 + g * 8 + lh * 4) = o4;
    }
}

// ---------------- output projection GEMM + bias, f32 out ----------------
__global__ __launch_bounds__(256) void gemm_out(
    const unsigned short* __restrict__ ab,
    const unsigned short* __restrict__ wob,
    const float* __restrict__ bo,
    float* __restrict__ out)
{
    __shared__ __align__(16) unsigned short Al[128 * 32];
    __shared__ __align__(16) unsigned short Bl[128 * 32];

    const int tid = threadIdx.x;
    const int lane = tid & 63;
    const int w = tid >> 6;
    const int wr = w >> 1, wc = w & 1;
    const int lr = lane & 15, lg = lane >> 4;
    const int m0 = blockIdx.y * 128;
    const int n0 = blockIdx.x * 128;
    const int srow = tid >> 2, sseg = tid & 3;
    const int wbase = tid & 192;

    f32x4 acc[4][4] = {};

    for (int k0 = 0; k0 < 1024; k0 += 32) {
        __syncthreads();
#pragma unroll
        for (int p = 0; p < 2; ++p) {
            const int row = srow + p * 64;
            gload16(ab + (size_t)(m0 + row) * 1024 + k0 + sseg * 8, Al + (p * 256 + wbase) * 8);
            gload16(wob + (size_t)(n0 + row) * 1024 + k0 + sseg * 8, Bl + (p * 256 + wbase) * 8);
        }
        __syncthreads();
        bf16x8 af[4], bfr[4];
#pragma unroll
        for (int mt = 0; mt < 4; ++mt)
            af[mt] = *(const bf16x8*)(Al + (wr * 64 + mt * 16 + lr) * 32 + lg * 8);
#pragma unroll
        for (int nt = 0; nt < 4; ++nt)
            bfr[nt] = *(const bf16x8*)(Bl + (wc * 64 + nt * 16 + lr) * 32 + lg * 8);
#pragma unroll
        for (int mt = 0; mt < 4; ++mt)
#pragma unroll
            for (int nt = 0; nt < 4; ++nt)
                acc[mt][nt] = __builtin_amdgcn_mfma_f32_16x16x32_bf16(af[mt], bfr[nt], acc[mt][nt], 0, 0, 0);
    }

#pragma unroll
    for (int mt = 0; mt < 4; ++mt) {
#pragma unroll
        for (int nt = 0; nt < 4; ++nt) {
            const int col = n0 + wc * 64 + nt * 16 + lr;
            const float bcol = bo[col];
#pragma unroll
            for (int r = 0; r < 4; ++r) {
                const int mrow = m0 + wr * 64 + mt * 16 + lg * 4 + r;
                out[(size_t)mrow * 1024 + col] = acc[mt][nt][r] + bcol;
            }
        }
    }
}

extern "C" void kernel_launch(void* const* d_in, const int* in_sizes, int n_in,
                              void* d_out, int out_size, void* d_ws, size_t ws_size,
                              hipStream_t stream) {
    const float* x    = (const float*)d_in[0];
    const float* cosT = (const float*)d_in[1];
    const float* sinT = (const float*)d_in[2];
    const float* Wq   = (const float*)d_in[3];
    const float* bq   = (const float*)d_in[4];
    const float* Wk   = (const float*)d_in[5];
    const float* bk   = (const float*)d_in[6];
    const float* Wv   = (const float*)d_in[7];
    const float* bv   = (const float*)d_in[8];
    const float* Wo   = (const float*)d_in[9];
    const float* bo   = (const float*)d_in[10];
    float* out = (float*)d_out;

    char* ws = (char*)d_ws;
    unsigned short* xb    = (unsigned short*)(ws + 0);           // 8 MB, dead after gemm_qkv
    unsigned short* attnb = (unsigned short*)(ws + 0);           // overlays xb
    unsigned short* wob   = (unsigned short*)(ws + 8388608);     // 2 MB
    unsigned short* wqb   = (unsigned short*)(ws + 10485760);
    unsigned short* wkb   = (unsigned short*)(ws + 12582912);
    unsigned short* wvb   = (unsigned short*)(ws + 14680064);
    unsigned short* Qb    = (unsigned short*)(ws + 16777216);    // 8 MB
    unsigned short* Kb    = (unsigned short*)(ws + 25165824);    // 8 MB
    unsigned short* Vtg   = (unsigned short*)(ws + 33554432);    // 8 MB, [bh][64][2048]

    cvt_all<<<dim3(4096, 5), 256, 0, stream>>>(x, Wq, Wk, Wv, Wo, xb, wqb, wkb, wvb, wob);
    gemm_qkv<<<dim3(8, 32, 3), 256, 0, stream>>>(xb, wqb, wkb, wvb, bq, bk, bv,
                                                 cosT, sinT, Qb, Kb, Vtg);
    attn_fwd<<<dim3(32, 16), 256, 0, stream>>>(Qb, Kb, Vtg, attnb);
    gemm_out<<<dim3(8, 32, 1), 256, 0, stream>>>(attnb, wob, bo, out);
}